// Round 2
// baseline (1966.403 us; speedup 1.0000x reference)
//
#include <hip/hip_runtime.h>
#include <cstddef>
#include <cstdint>

// ---------------------------------------------------------------------------
// N=50000 nodes, E=1,650,000 edges (incl. self loops). Stages (in,out):
// (512,384),(384,256),(256,128), FC 128->128.
// Pipeline (all activations/weights fp16, accumulation fp32):
//   convert -> [per stage: MFMA GEMM (panel-major out) -> panel agg] x6 -> FC
// GEMM-first restructuring: (A h) W^T == A (h W^T); row scales commute.
// R2: aggregation is column-separable -> split into 32-col panels (3.2 MB,
//     fits one XCD's 4 MB L2). Z stored PANEL-MAJOR [D/32][Mpad][32] by the
//     GEMM epilogue; one launch per panel serializes passes so gathers hit L2.
//     CSR index loads are nontemporal (no L2 pollution); agg output stores nt.
// ---------------------------------------------------------------------------

typedef _Float16 h8 __attribute__((ext_vector_type(8)));
typedef _Float16 h4 __attribute__((ext_vector_type(4)));
typedef float f32x4 __attribute__((ext_vector_type(4)));

// ---------------- degree / CSR build ----------------

__global__ __launch_bounds__(256) void deg_kernel(
    const int* __restrict__ src, const int* __restrict__ dst,
    int* __restrict__ in_deg, int* __restrict__ out_deg, int E) {
  int e = blockIdx.x * 256 + threadIdx.x;
  if (e < E) {
    atomicAdd(&in_deg[dst[e]], 1);
    atomicAdd(&out_deg[src[e]], 1);
  }
}

__global__ __launch_bounds__(1024) void scan_kernel(
    const int* __restrict__ deg, int* __restrict__ row_ptr, int n) {
  __shared__ int buf[1024];
  __shared__ int carry_s;
  if (threadIdx.x == 0) carry_s = 0;
  __syncthreads();
  for (int base = 0; base < n; base += 1024) {
    int i = base + (int)threadIdx.x;
    int v = (i < n) ? deg[i] : 0;
    buf[threadIdx.x] = v;
    __syncthreads();
    #pragma unroll
    for (int off = 1; off < 1024; off <<= 1) {
      int t = 0;
      if ((int)threadIdx.x >= off) t = buf[threadIdx.x - off];
      __syncthreads();
      buf[threadIdx.x] += t;
      __syncthreads();
    }
    int incl  = buf[threadIdx.x];
    int carry = carry_s;
    int total = buf[1023];
    __syncthreads();
    if (i < n) row_ptr[i] = carry + incl - v;
    if (threadIdx.x == 0) carry_s = carry + total;
    __syncthreads();
  }
  if (threadIdx.x == 0) row_ptr[n] = carry_s;
}

__global__ __launch_bounds__(256) void scatter_kernel(
    const int* __restrict__ src, const int* __restrict__ dst,
    const int* __restrict__ row_ptr, int* __restrict__ cnt,
    int* __restrict__ csr, int E) {
  int e = blockIdx.x * 256 + threadIdx.x;
  if (e < E) {
    int d = dst[e];
    int pos = row_ptr[d] + atomicAdd(&cnt[d], 1);
    csr[pos] = src[e];
  }
}

__global__ __launch_bounds__(256) void scaler_kernel(
    const int* __restrict__ in_deg, const int* __restrict__ out_deg,
    float* __restrict__ inv_src, float* __restrict__ inv_dst,
    float* __restrict__ inv_den, int n) {
  int i = blockIdx.x * 256 + threadIdx.x;
  if (i < n) {
    float od = (float)out_deg[i];
    float id = (float)in_deg[i];
    inv_src[i] = rsqrtf(od > 0.f ? od : 1.0f);
    inv_dst[i] = rsqrtf(id > 0.f ? id : 1.0f);
    inv_den[i] = 1.0f / (id + 1.0f);
  }
}

// ---------------- fp32 -> fp16 conversion (pad region zeroed) ----------------

__global__ __launch_bounds__(256) void cvt_kernel(
    const float* __restrict__ in, _Float16* __restrict__ out,
    long n_in, long n_pad) {
  long i = ((long)blockIdx.x * 256 + (long)threadIdx.x) * 4;
  if (i >= n_pad) return;
  float4 v = (i < n_in) ? *(const float4*)(in + i) : make_float4(0.f, 0.f, 0.f, 0.f);
  h4 h = {(_Float16)v.x, (_Float16)v.y, (_Float16)v.z, (_Float16)v.w};
  *(h4*)(out + i) = h;
}

// ---------------- async global->LDS helper (width=16, literal per guide) ----

__device__ __forceinline__ void gload_lds16(const _Float16* g, _Float16* l) {
  __builtin_amdgcn_global_load_lds(
      (const __attribute__((address_space(1))) void*)g,
      (__attribute__((address_space(3))) void*)l, 16, 0, 0);
}

// ---------------- fp16 MFMA GEMM: C[M x Nc] = A[M x K] @ W^T ----------------
// A padded to a multiple of 128 rows (pad rows hold finite junk; their C rows
// are discarded by the m<Mstore store guard). W row-major [Nc x K]. Epilogue:
// optional per-row scale + bias; output either row-major (pstride=0) or
// panel-major [Nc/32][pstride/32... i.e. (c>>5)*pstride + m*32 + (c&31)].
// 256 thr = 4 waves (2x2), 64x64/wave, 16x16x32_f16 MFMA, BK=32, LDS 2x8KB.
// Staging via global_load_lds width=16: LDS byte offset == tid*16 (linear in
// lane order, wave-uniform base + lane*16 as HW requires).
// Fragment layouts (HW-verified, guide §3): A/B lane l: idx=l&15, k=(l>>4)*8+j;
// C/D lane l: col=l&15, row=(l>>4)*4+reg.

template <typename OutT>
__global__ __launch_bounds__(256) void hgemm(
    const _Float16* __restrict__ A, const _Float16* __restrict__ W,
    OutT* __restrict__ C, int Mstore, int K, int Nc,
    const float* __restrict__ row_scale, const float* __restrict__ bias,
    size_t pstride) {
  __shared__ _Float16 As[128 * 32];
  __shared__ _Float16 Bs[128 * 32];
  const int tid = threadIdx.x;
  const int bm = blockIdx.x * 128, bn = blockIdx.y * 128;
  const int wave = tid >> 6, lane = tid & 63;
  const int wm = (wave & 1) * 64, wn = (wave >> 1) * 64;
  const int lrow = lane & 15, lq = lane >> 4;

  const int r0 = tid >> 2;
  const int cc = (tid & 3) * 8;
  const _Float16* Ag = A + (size_t)(bm + r0) * K + cc;
  const _Float16* Wg = W + (size_t)(bn + r0) * K + cc;
  const size_t rs64 = (size_t)64 * K;
  _Float16* As0 = As + tid * 8;
  _Float16* As1 = As + 64 * 32 + tid * 8;
  _Float16* Bs0 = Bs + tid * 8;
  _Float16* Bs1 = Bs + 64 * 32 + tid * 8;

  f32x4 acc[4][4];
  #pragma unroll
  for (int i = 0; i < 4; ++i)
    #pragma unroll
    for (int j = 0; j < 4; ++j) acc[i][j] = (f32x4){0.f, 0.f, 0.f, 0.f};

  for (int k0 = 0; k0 < K; k0 += 32) {
    __syncthreads();  // previous tile's ds_reads complete before overwrite
    gload_lds16(Ag + k0, As0);
    gload_lds16(Ag + rs64 + k0, As1);
    gload_lds16(Wg + k0, Bs0);
    gload_lds16(Wg + rs64 + k0, Bs1);
    __syncthreads();  // vmcnt(0) drained before s_barrier -> LDS ready
    h8 af[4], bf[4];
    #pragma unroll
    for (int i = 0; i < 4; ++i)
      af[i] = *(const h8*)(As + (wm + i * 16 + lrow) * 32 + lq * 8);
    #pragma unroll
    for (int j = 0; j < 4; ++j)
      bf[j] = *(const h8*)(Bs + (wn + j * 16 + lrow) * 32 + lq * 8);
    #pragma unroll
    for (int i = 0; i < 4; ++i)
      #pragma unroll
      for (int j = 0; j < 4; ++j)
        acc[i][j] = __builtin_amdgcn_mfma_f32_16x16x32_f16(af[i], bf[j], acc[i][j], 0, 0, 0);
  }

  #pragma unroll
  for (int i = 0; i < 4; ++i) {
    #pragma unroll
    for (int r = 0; r < 4; ++r) {
      const int m = bm + wm + i * 16 + lq * 4 + r;
      if (m < Mstore) {
        const float rsc = row_scale ? row_scale[m] : 1.0f;
        #pragma unroll
        for (int j = 0; j < 4; ++j) {
          const int c = bn + wn + j * 16 + lrow;
          float v = acc[i][j][r] * rsc;
          if (bias) v += bias[c];
          const size_t off = pstride
              ? ((size_t)(c >> 5) * pstride + (size_t)m * 32 + (size_t)(c & 31))
              : ((size_t)m * Nc + (size_t)c);
          C[off] = (OutT)v;
        }
      }
    }
  }
}

// ---------------- panel CSR aggregation ----------------
// One launch per 32-col panel p. Zpm is panel-major: row s's panel chunk is
// Zpm[p*Mpad*32 + s*32 .. +32) -- the whole pass touches one contiguous
// 3.2 MB region that fits a per-XCD L2. 4 lanes per node (16 B each); csr
// fetched 4-ahead per group (nontemporal -> no L2 pollution), broadcast via
// __shfl width 4; 4 gathers batched per step for ILP.
// out[node, p*32 + ...] = relu((sum_edges + SELF?Z[node]) * scale + bias), nt.

template <bool SELF>
__global__ __launch_bounds__(256) void agg_panel(
    const _Float16* __restrict__ Zpm, const int* __restrict__ row_ptr,
    const int* __restrict__ csr, const float* __restrict__ out_scale,
    const float* __restrict__ bias, _Float16* __restrict__ out,
    int n, int Mpad, int D, int panel) {
  const int gq = threadIdx.x >> 2;        // node-group within block, 0..63
  const int l4 = threadIdx.x & 3;         // lane within group
  const int node = blockIdx.x * 64 + gq;
  if (node >= n) return;

  const _Float16* Zp = Zpm + (size_t)panel * (size_t)Mpad * 32 + (size_t)l4 * 8;
  const int rs = row_ptr[node], re = row_ptr[node + 1];

  float acc[8];
  #pragma unroll
  for (int q = 0; q < 8; ++q) acc[q] = 0.f;

  for (int e = rs; e < re; e += 4) {
    int idx = e + l4;
    if (idx >= re) idx = re - 1;  // clamp; duplicate loads masked by nrem guards
    const int eid = __builtin_nontemporal_load(csr + idx);
    const int s0 = __shfl(eid, 0, 4);
    const int s1 = __shfl(eid, 1, 4);
    const int s2 = __shfl(eid, 2, 4);
    const int s3 = __shfl(eid, 3, 4);
    h8 t0 = *(const h8*)(Zp + (size_t)s0 * 32);
    h8 t1 = *(const h8*)(Zp + (size_t)s1 * 32);
    h8 t2 = *(const h8*)(Zp + (size_t)s2 * 32);
    h8 t3 = *(const h8*)(Zp + (size_t)s3 * 32);
    const int nrem = re - e;
    #pragma unroll
    for (int q = 0; q < 8; ++q) acc[q] += (float)t0[q];
    if (nrem > 1) {
      #pragma unroll
      for (int q = 0; q < 8; ++q) acc[q] += (float)t1[q];
    }
    if (nrem > 2) {
      #pragma unroll
      for (int q = 0; q < 8; ++q) acc[q] += (float)t2[q];
    }
    if (nrem > 3) {
      #pragma unroll
      for (int q = 0; q < 8; ++q) acc[q] += (float)t3[q];
    }
  }

  if (SELF) {
    h8 ts = *(const h8*)(Zp + (size_t)node * 32);
    #pragma unroll
    for (int q = 0; q < 8; ++q) acc[q] += (float)ts[q];
  }

  const float osc = out_scale[node];
  const int c0 = panel * 32 + l4 * 8;
  h8 r;
  #pragma unroll
  for (int q = 0; q < 8; ++q) {
    float x = acc[q] * osc + bias[c0 + q];
    r[q] = (_Float16)fmaxf(x, 0.f);
  }
  __builtin_nontemporal_store(r, (h8*)(out + (size_t)node * D + c0));
}

// ---------------- host-side orchestration ----------------

static void launch_cvt(const float* in, _Float16* out, long n_in, long n_pad,
                       hipStream_t st) {
  long thr = n_pad / 4;
  cvt_kernel<<<(int)((thr + 255) / 256), 256, 0, st>>>(in, out, n_in, n_pad);
}

extern "C" void kernel_launch(void* const* d_in, const int* in_sizes, int n_in,
                              void* d_out, int out_size, void* d_ws, size_t ws_size,
                              hipStream_t stream) {
  const float* features = (const float*)d_in[0];
  const int*   src      = (const int*)d_in[1];
  const int*   dst      = (const int*)d_in[2];
  const float* wsrc[7] = {(const float*)d_in[3],  (const float*)d_in[5],
                          (const float*)d_in[7],  (const float*)d_in[9],
                          (const float*)d_in[11], (const float*)d_in[13],
                          (const float*)d_in[15]};  // sw0,gw0,sw1,gw1,sw2,gw2,fc
  const float* sb[3] = {(const float*)d_in[4],  (const float*)d_in[8],  (const float*)d_in[12]};
  const float* gb[3] = {(const float*)d_in[6],  (const float*)d_in[10], (const float*)d_in[14]};
  const float* fc_b  = (const float*)d_in[16];

  const int N = in_sizes[0] / 512;
  const int E = in_sizes[1];
  const int MB = (N + 127) / 128;
  const int Mpad = MB * 128;

  const int wcnt[7] = {384 * 512, 384 * 384, 256 * 384, 256 * 256,
                       128 * 256, 128 * 128, 128 * 128};

  // workspace layout (fp16 buffers first, 16B-aligned throughout)
  char* ws = (char*)d_ws;
  _Float16* featH = (_Float16*)ws;                       // Mpad*512
  _Float16* hA    = featH + (size_t)Mpad * 512;          // Mpad*384 (activations, node-major)
  _Float16* hB    = hA + (size_t)Mpad * 384;             // Mpad*384 (Z, panel-major)
  _Float16* wH[7];
  {
    _Float16* p = hB + (size_t)Mpad * 384;
    for (int i = 0; i < 7; ++i) { wH[i] = p; p += wcnt[i]; }
  }
  int* csr     = (int*)(wH[6] + wcnt[6]);                // E ints
  int* rp      = csr + E;                                // N+1
  int* in_dg   = rp + (N + 1);                           // N (zeroed)
  int* out_dg  = in_dg + N;                              // N (zeroed)
  int* cnt     = out_dg + N;                             // N (zeroed)
  float* inv_src = (float*)(cnt + N);                    // N
  float* inv_dst = inv_src + N;                          // N
  float* inv_den = inv_dst + N;                          // N

  size_t totw = 0; for (int i = 0; i < 7; ++i) totw += wcnt[i];
  size_t needed = ((size_t)Mpad * (512 + 384 + 384) + totw) * 2 +
                  ((size_t)E + (N + 1) + 6 * (size_t)N) * 4;
  if (ws_size < needed) return;

  (void)hipMemsetAsync(in_dg, 0, sizeof(int) * 3 * (size_t)N, stream);

  const int eb = (E + 255) / 256;
  const int nb = (N + 255) / 256;
  deg_kernel<<<eb, 256, 0, stream>>>(src, dst, in_dg, out_dg, E);
  scan_kernel<<<1, 1024, 0, stream>>>(in_dg, rp, N);
  scatter_kernel<<<eb, 256, 0, stream>>>(src, dst, rp, cnt, csr, E);
  scaler_kernel<<<nb, 256, 0, stream>>>(in_dg, out_dg, inv_src, inv_dst, inv_den, N);

  // conversions
  launch_cvt(features, featH, (long)N * 512, (long)Mpad * 512, stream);
  for (int i = 0; i < 7; ++i) launch_cvt(wsrc[i], wH[i], wcnt[i], wcnt[i], stream);

  const size_t pstride = (size_t)Mpad * 32;  // panel-major panel stride (elems)
  const int dout[3] = {384, 256, 128};
  const _Float16* h = featH;
  int K = 512;
  for (int s = 0; s < 3; ++s) {
    const int D = dout[s];
    dim3 gg(MB, D / 128);
    const int ab = (N + 63) / 64;
    // SAGE: Z = h @ sw^T (panel-major); h' = relu((sum_in Z + Z_self)*inv_den + sb)
    hgemm<_Float16><<<gg, 256, 0, stream>>>(h, wH[2 * s], hB, Mpad, K, D,
                                            nullptr, nullptr, pstride);
    for (int p = 0; p < D / 32; ++p)
      agg_panel<true><<<ab, 256, 0, stream>>>(hB, rp, csr, inv_den, sb[s], hA,
                                              N, Mpad, D, p);
    // GraphConv: Z = (h'*inv_src) @ gw^T (panel-major); h'' = relu((sum_in Z)*inv_dst + gb)
    hgemm<_Float16><<<gg, 256, 0, stream>>>(hA, wH[2 * s + 1], hB, Mpad, D, D,
                                            inv_src, nullptr, pstride);
    for (int p = 0; p < D / 32; ++p)
      agg_panel<false><<<ab, 256, 0, stream>>>(hB, rp, csr, inv_dst, gb[s], hA,
                                               N, Mpad, D, p);
    h = hA;
    K = D;
  }
  // final FC: fp32 out + bias, no relu, row-major
  dim3 gf(MB, 1);
  hgemm<float><<<gf, 256, 0, stream>>>(h, wH[6], (float*)d_out, N, 128, 128,
                                       nullptr, fc_b, 0);
}

// Round 3
// 1192.407 us; speedup vs baseline: 1.6491x; 1.6491x over previous
//
#include <hip/hip_runtime.h>
#include <cstddef>
#include <cstdint>

// ---------------------------------------------------------------------------
// N=50000 nodes, E=1,650,000 edges (incl. self loops). Stages (in,out):
// (512,384),(384,256),(256,128), FC 128->128.
// Pipeline (all activations/weights fp16, accumulation fp32):
//   convert -> [per stage: MFMA GEMM -> CSR agg] x6 -> MFMA FC (fp32 out)
// GEMM-first restructuring: (A h) W^T == A (h W^T); row scales commute.
// R3: panel agg reverted (R2 regression: launch gaps + 12x per-edge overhead).
//     CSR build rebuilt: in-deg atomic returns edge ordinal (scatter becomes
//     atomic-free); out-deg via LDS histogram (no global RMW); 3-phase scan
//     replaces single-block scan; scaler fused; weight cvts merged.
// ---------------------------------------------------------------------------

typedef _Float16 h8 __attribute__((ext_vector_type(8)));
typedef _Float16 h4 __attribute__((ext_vector_type(4)));
typedef float f32x4 __attribute__((ext_vector_type(4)));

#define HB 64  // histogram blocks

// ---------------- degree / CSR build ----------------

// in-degree count; atomic return value = within-node ordinal of this edge.
__global__ __launch_bounds__(256) void deg_kernel(
    const int* __restrict__ dst, int* __restrict__ in_deg,
    int* __restrict__ ord, int E) {
  int e = blockIdx.x * 256 + threadIdx.x;
  if (e < E) ord[e] = atomicAdd(&in_deg[dst[e]], 1);
}

// out-degree histogram: 64 blocks, packed 2 x u16 bins per u32 in LDS
// (per-block count <= E/64 = 25782 < 65536, no overflow). No global RMW.
__global__ __launch_bounds__(1024) void histo_out_kernel(
    const int* __restrict__ src, uint32_t* __restrict__ H, int E, int bins2) {
  __shared__ uint32_t hh[25088];  // 100 KB
  for (int i = threadIdx.x; i < bins2; i += 1024) hh[i] = 0;
  __syncthreads();
  const int C = (E + HB - 1) / HB;
  const int base = blockIdx.x * C;
  int lim = base + C; if (lim > E) lim = E;
  for (int e = base + (int)threadIdx.x; e < lim; e += 1024) {
    int s = src[e];
    atomicAdd(&hh[s >> 1], 1u << ((s & 1) * 16));
  }
  __syncthreads();
  uint32_t* out = H + (size_t)blockIdx.x * bins2;
  for (int i = threadIdx.x; i < bins2; i += 1024) out[i] = hh[i];
}

__global__ __launch_bounds__(256) void reduce_out_kernel(
    const uint32_t* __restrict__ H, int* __restrict__ out_deg,
    int bins2, int n) {
  int i = blockIdx.x * 256 + threadIdx.x;
  if (i >= bins2) return;
  uint32_t lo = 0, hi = 0;
  for (int b = 0; b < HB; ++b) {
    uint32_t v = H[(size_t)b * bins2 + i];
    lo += v & 0xFFFFu;
    hi += v >> 16;
  }
  out_deg[2 * i] = (int)lo;
  if (2 * i + 1 < n) out_deg[2 * i + 1] = (int)hi;
}

// ---- 3-phase scan of in_deg -> row_ptr (nb <= 256 blocks of 256) ----

__global__ __launch_bounds__(256) void scan_a(
    const int* __restrict__ deg, int* __restrict__ bsum, int n) {
  __shared__ int s[256];
  int i = blockIdx.x * 256 + threadIdx.x;
  s[threadIdx.x] = (i < n) ? deg[i] : 0;
  __syncthreads();
  #pragma unroll
  for (int off = 128; off > 0; off >>= 1) {
    if ((int)threadIdx.x < off) s[threadIdx.x] += s[threadIdx.x + off];
    __syncthreads();
  }
  if (threadIdx.x == 0) bsum[blockIdx.x] = s[0];
}

__global__ __launch_bounds__(256) void scan_b(
    int* __restrict__ bsum, int* __restrict__ rp, int nb, int n) {
  __shared__ int s[256];
  const int t = threadIdx.x;
  int v = (t < nb) ? bsum[t] : 0;
  s[t] = v;
  __syncthreads();
  #pragma unroll
  for (int off = 1; off < 256; off <<= 1) {
    int a = (t >= off) ? s[t - off] : 0;
    __syncthreads();
    s[t] += a;
    __syncthreads();
  }
  bsum[256 + t] = s[t] - v;  // exclusive block offset
  if (t == 255) rp[n] = s[255];
}

// block-local scan + write row_ptr; degree scalers fused.
__global__ __launch_bounds__(256) void scan_c(
    const int* __restrict__ in_deg, const int* __restrict__ out_deg,
    const int* __restrict__ bsum, int* __restrict__ rp,
    float* __restrict__ inv_src, float* __restrict__ inv_dst,
    float* __restrict__ inv_den, int n) {
  __shared__ int s[256];
  const int t = threadIdx.x;
  const int i = blockIdx.x * 256 + t;
  int v = (i < n) ? in_deg[i] : 0;
  s[t] = v;
  __syncthreads();
  #pragma unroll
  for (int off = 1; off < 256; off <<= 1) {
    int a = (t >= off) ? s[t - off] : 0;
    __syncthreads();
    s[t] += a;
    __syncthreads();
  }
  if (i < n) {
    rp[i] = bsum[256 + blockIdx.x] + s[t] - v;
    float od = (float)out_deg[i];
    float id = (float)v;
    inv_src[i] = rsqrtf(od > 0.f ? od : 1.0f);
    inv_dst[i] = rsqrtf(id > 0.f ? id : 1.0f);
    inv_den[i] = 1.0f / (id + 1.0f);
  }
}

// atomic-free scatter using precomputed ordinals.
__global__ __launch_bounds__(256) void scatter_kernel(
    const int* __restrict__ src, const int* __restrict__ dst,
    const int* __restrict__ rp, const int* __restrict__ ord,
    int* __restrict__ csr, int E) {
  int e = blockIdx.x * 256 + threadIdx.x;
  if (e < E) csr[rp[dst[e]] + ord[e]] = src[e];
}

// ---------------- fp32 -> fp16 conversion ----------------

__global__ __launch_bounds__(256) void cvt_kernel(
    const float* __restrict__ in, _Float16* __restrict__ out,
    long n_in, long n_pad) {
  long i = ((long)blockIdx.x * 256 + (long)threadIdx.x) * 4;
  if (i >= n_pad) return;
  float4 v = (i < n_in) ? *(const float4*)(in + i) : make_float4(0.f, 0.f, 0.f, 0.f);
  h4 h = {(_Float16)v.x, (_Float16)v.y, (_Float16)v.z, (_Float16)v.w};
  *(h4*)(out + i) = h;
}

// all 7 weight conversions in one launch (sizes all multiples of 4)
struct WArgs {
  const float* s[7];
  _Float16* d[7];
  int n[7];
};

__global__ __launch_bounds__(256) void wcvt_kernel(WArgs a) {
  const int w = blockIdx.y;
  long i = ((long)blockIdx.x * 256 + (long)threadIdx.x) * 4;
  if (i >= a.n[w]) return;
  float4 v = *(const float4*)(a.s[w] + i);
  h4 h = {(_Float16)v.x, (_Float16)v.y, (_Float16)v.z, (_Float16)v.w};
  *(h4*)(a.d[w] + i) = h;
}

// ---------------- async global->LDS helper (width=16, literal per guide) ----

__device__ __forceinline__ void gload_lds16(const _Float16* g, _Float16* l) {
  __builtin_amdgcn_global_load_lds(
      (const __attribute__((address_space(1))) void*)g,
      (__attribute__((address_space(3))) void*)l, 16, 0, 0);
}

// ---------------- fp16 MFMA GEMM: C[M x Nc] = A[M x K] @ W^T ----------------
// A padded to a multiple of 128 rows (pad rows hold finite junk; their C rows
// are discarded by the m<Mstore store guard). W row-major [Nc x K]. Epilogue:
// optional per-row scale + bias. 256 thr = 4 waves (2x2), 64x64/wave,
// 16x16x32_f16 MFMA, BK=32, LDS 2x8KB. Staging via global_load_lds width=16:
// LDS byte offset == tid*16 (linear in lane order as HW requires).
// Fragment layouts (HW-verified, guide §3): A/B lane l: idx=l&15, k=(l>>4)*8+j;
// C/D lane l: col=l&15, row=(l>>4)*4+reg.

template <typename OutT>
__global__ __launch_bounds__(256) void hgemm(
    const _Float16* __restrict__ A, const _Float16* __restrict__ W,
    OutT* __restrict__ C, int Mstore, int K, int Nc,
    const float* __restrict__ row_scale, const float* __restrict__ bias) {
  __shared__ _Float16 As[128 * 32];
  __shared__ _Float16 Bs[128 * 32];
  const int tid = threadIdx.x;
  const int bm = blockIdx.x * 128, bn = blockIdx.y * 128;
  const int wave = tid >> 6, lane = tid & 63;
  const int wm = (wave & 1) * 64, wn = (wave >> 1) * 64;
  const int lrow = lane & 15, lq = lane >> 4;

  const int r0 = tid >> 2;
  const int cc = (tid & 3) * 8;
  const _Float16* Ag = A + (size_t)(bm + r0) * K + cc;
  const _Float16* Wg = W + (size_t)(bn + r0) * K + cc;
  const size_t rs64 = (size_t)64 * K;
  _Float16* As0 = As + tid * 8;
  _Float16* As1 = As + 64 * 32 + tid * 8;
  _Float16* Bs0 = Bs + tid * 8;
  _Float16* Bs1 = Bs + 64 * 32 + tid * 8;

  f32x4 acc[4][4];
  #pragma unroll
  for (int i = 0; i < 4; ++i)
    #pragma unroll
    for (int j = 0; j < 4; ++j) acc[i][j] = (f32x4){0.f, 0.f, 0.f, 0.f};

  for (int k0 = 0; k0 < K; k0 += 32) {
    __syncthreads();  // previous tile's ds_reads complete before overwrite
    gload_lds16(Ag + k0, As0);
    gload_lds16(Ag + rs64 + k0, As1);
    gload_lds16(Wg + k0, Bs0);
    gload_lds16(Wg + rs64 + k0, Bs1);
    __syncthreads();  // vmcnt(0) drained before s_barrier -> LDS ready
    h8 af[4], bf[4];
    #pragma unroll
    for (int i = 0; i < 4; ++i)
      af[i] = *(const h8*)(As + (wm + i * 16 + lrow) * 32 + lq * 8);
    #pragma unroll
    for (int j = 0; j < 4; ++j)
      bf[j] = *(const h8*)(Bs + (wn + j * 16 + lrow) * 32 + lq * 8);
    #pragma unroll
    for (int i = 0; i < 4; ++i)
      #pragma unroll
      for (int j = 0; j < 4; ++j)
        acc[i][j] = __builtin_amdgcn_mfma_f32_16x16x32_f16(af[i], bf[j], acc[i][j], 0, 0, 0);
  }

  #pragma unroll
  for (int i = 0; i < 4; ++i) {
    #pragma unroll
    for (int r = 0; r < 4; ++r) {
      const int m = bm + wm + i * 16 + lq * 4 + r;
      if (m < Mstore) {
        const float rsc = row_scale ? row_scale[m] : 1.0f;
        OutT* crow = C + (size_t)m * Nc + bn + wn + lrow;
        #pragma unroll
        for (int j = 0; j < 4; ++j) {
          float v = acc[i][j][r] * rsc;
          if (bias) v += bias[bn + wn + j * 16 + lrow];
          crow[j * 16] = (OutT)v;
        }
      }
    }
  }
}

// ---------------- CSR aggregation, fp16 gather / fp32 accumulate ----------------
// out[n] = relu(((sum_{e:dst=n} Z[csr[e]]) (+ Z[n] if SELF)) * out_scale[n] + bias)
// 16 lanes per node; 16B gathers; all lanes active for D in {384,256,128}.
// (R1/R2 variants showed this is fabric-throughput-bound, not latency-bound;
// keep the simple 36-VGPR form.)

template <int D, bool SELF>
__global__ __launch_bounds__(256) void agg_h(
    const _Float16* __restrict__ Z, const int* __restrict__ row_ptr,
    const int* __restrict__ csr, const float* __restrict__ out_scale,
    const float* __restrict__ bias, _Float16* __restrict__ out, int n) {
  constexpr int CH = D / 8;       // 16B chunks per row (48/32/16)
  constexpr int GROUP = 16;
  constexpr int NV = CH / GROUP;  // 3/2/1 chunks per lane
  const int gid = threadIdx.x >> 4;
  const int lane = threadIdx.x & 15;
  const int node = blockIdx.x * 16 + gid;
  if (node >= n) return;

  const int rs = row_ptr[node], re = row_ptr[node + 1];

  float acc[NV][8];
  #pragma unroll
  for (int v = 0; v < NV; ++v)
    #pragma unroll
    for (int q = 0; q < 8; ++q) acc[v][q] = 0.f;

  for (int e = rs; e < re; e += GROUP) {
    int m = re - e; if (m > GROUP) m = GROUP;
    int eid = (lane < m) ? csr[e + lane] : 0;
    for (int j = 0; j < m; ++j) {
      int s = __shfl(eid, j, GROUP);
      const h8* zr = (const h8*)(Z + (size_t)s * D);
      #pragma unroll
      for (int v = 0; v < NV; ++v) {
        h8 t = zr[lane + v * GROUP];
        #pragma unroll
        for (int q = 0; q < 8; ++q) acc[v][q] += (float)t[q];
      }
    }
  }

  const float osc = out_scale[node];
  const h8* zs = (const h8*)(Z + (size_t)node * D);
  _Float16* orow = out + (size_t)node * D;
  #pragma unroll
  for (int v = 0; v < NV; ++v) {
    const int idx = lane + v * GROUP;
    if (SELF) {
      h8 t = zs[idx];
      #pragma unroll
      for (int q = 0; q < 8; ++q) acc[v][q] += (float)t[q];
    }
    h8 r;
    #pragma unroll
    for (int q = 0; q < 8; ++q) {
      float x = acc[v][q] * osc + bias[idx * 8 + q];
      r[q] = (_Float16)fmaxf(x, 0.f);
    }
    *(h8*)(orow + idx * 8) = r;
  }
}

// ---------------- host-side orchestration ----------------

extern "C" void kernel_launch(void* const* d_in, const int* in_sizes, int n_in,
                              void* d_out, int out_size, void* d_ws, size_t ws_size,
                              hipStream_t stream) {
  const float* features = (const float*)d_in[0];
  const int*   src      = (const int*)d_in[1];
  const int*   dst      = (const int*)d_in[2];
  const float* wsrc[7] = {(const float*)d_in[3],  (const float*)d_in[5],
                          (const float*)d_in[7],  (const float*)d_in[9],
                          (const float*)d_in[11], (const float*)d_in[13],
                          (const float*)d_in[15]};  // sw0,gw0,sw1,gw1,sw2,gw2,fc
  const float* sb[3] = {(const float*)d_in[4],  (const float*)d_in[8],  (const float*)d_in[12]};
  const float* gb[3] = {(const float*)d_in[6],  (const float*)d_in[10], (const float*)d_in[14]};
  const float* fc_b  = (const float*)d_in[16];

  const int N = in_sizes[0] / 512;
  const int E = in_sizes[1];
  const int MB = (N + 127) / 128;
  const int Mpad = MB * 128;
  const int bins2 = (N + 1) / 2;
  if (bins2 > 25088) return;  // LDS histogram capacity

  const int wcnt[7] = {384 * 512, 384 * 384, 256 * 384, 256 * 256,
                       128 * 256, 128 * 128, 128 * 128};

  // workspace layout (fp16 buffers first, 16B-aligned throughout)
  char* ws = (char*)d_ws;
  _Float16* featH = (_Float16*)ws;                       // Mpad*512
  _Float16* hA    = featH + (size_t)Mpad * 512;          // Mpad*384 (activations)
  _Float16* hB    = hA + (size_t)Mpad * 384;             // Mpad*384 (Z)
  _Float16* wH[7];
  {
    _Float16* p = hB + (size_t)Mpad * 384;
    for (int i = 0; i < 7; ++i) { wH[i] = p; p += wcnt[i]; }
  }
  int* csr     = (int*)(wH[6] + wcnt[6]);                // E ints
  int* rp      = csr + E;                                // N+1
  int* in_dg   = rp + (N + 1);                           // N (zeroed)
  int* out_dg  = in_dg + N;                              // N
  int* sblk    = out_dg + N;                             // N (scan scratch, needs 512)
  float* inv_src = (float*)(sblk + N);                   // N
  float* inv_dst = inv_src + N;                          // N
  float* inv_den = inv_dst + N;                          // N

  // CSR-build scratch aliased into hB (consumed before first GEMM writes hB):
  // ord(E ints) + H(HB*bins2 u32) = ~13 MB <= 38 MB.
  int*      ord = (int*)hB;
  uint32_t* H64 = (uint32_t*)(ord + E);

  size_t totw = 0; for (int i = 0; i < 7; ++i) totw += wcnt[i];
  size_t needed = ((size_t)Mpad * (512 + 384 + 384) + totw) * 2 +
                  ((size_t)E + (N + 1) + 6 * (size_t)N) * 4;
  if (ws_size < needed) return;

  (void)hipMemsetAsync(in_dg, 0, sizeof(int) * (size_t)N, stream);

  const int eb = (E + 255) / 256;
  const int nb256 = (N + 255) / 256;   // <= 256 for N <= 65536

  deg_kernel<<<eb, 256, 0, stream>>>(dst, in_dg, ord, E);
  histo_out_kernel<<<HB, 1024, 0, stream>>>(src, H64, E, bins2);
  reduce_out_kernel<<<(bins2 + 255) / 256, 256, 0, stream>>>(H64, out_dg, bins2, N);
  scan_a<<<nb256, 256, 0, stream>>>(in_dg, sblk, N);
  scan_b<<<1, 256, 0, stream>>>(sblk, rp, nb256, N);
  scan_c<<<nb256, 256, 0, stream>>>(in_dg, out_dg, sblk, rp,
                                    inv_src, inv_dst, inv_den, N);
  scatter_kernel<<<eb, 256, 0, stream>>>(src, dst, rp, ord, csr, E);

  // conversions (featH is independent of the hB-aliased scratch)
  {
    long thr = (long)Mpad * 512 / 4;
    cvt_kernel<<<(int)((thr + 255) / 256), 256, 0, stream>>>(
        features, featH, (long)N * 512, (long)Mpad * 512);
    WArgs wa;
    int maxn = 0;
    for (int i = 0; i < 7; ++i) {
      wa.s[i] = wsrc[i]; wa.d[i] = wH[i]; wa.n[i] = wcnt[i];
      if (wcnt[i] > maxn) maxn = wcnt[i];
    }
    dim3 wg((maxn / 4 + 255) / 256, 7);
    wcvt_kernel<<<wg, 256, 0, stream>>>(wa);
  }

  const int dout[3] = {384, 256, 128};
  const _Float16* h = featH;
  int K = 512;
  for (int s = 0; s < 3; ++s) {
    const int D = dout[s];
    dim3 gg(MB, D / 128);
    const int ab = (N + 15) / 16;
    // SAGE: Z = h @ sw^T ; h' = relu((sum_in Z + Z_self)*inv_den + sb)
    hgemm<_Float16><<<gg, 256, 0, stream>>>(h, wH[2 * s], hB, Mpad, K, D, nullptr, nullptr);
    if (D == 384)      agg_h<384, true><<<ab, 256, 0, stream>>>(hB, rp, csr, inv_den, sb[s], hA, N);
    else if (D == 256) agg_h<256, true><<<ab, 256, 0, stream>>>(hB, rp, csr, inv_den, sb[s], hA, N);
    else               agg_h<128, true><<<ab, 256, 0, stream>>>(hB, rp, csr, inv_den, sb[s], hA, N);
    // GraphConv: Z = (h'*inv_src) @ gw^T ; h'' = relu((sum_in Z)*inv_dst + gb)
    hgemm<_Float16><<<gg, 256, 0, stream>>>(hA, wH[2 * s + 1], hB, Mpad, D, D, inv_src, nullptr);
    if (D == 384)      agg_h<384, false><<<ab, 256, 0, stream>>>(hB, rp, csr, inv_dst, gb[s], hA, N);
    else if (D == 256) agg_h<256, false><<<ab, 256, 0, stream>>>(hB, rp, csr, inv_dst, gb[s], hA, N);
    else               agg_h<128, false><<<ab, 256, 0, stream>>>(hB, rp, csr, inv_dst, gb[s], hA, N);
    h = hA;
    K = D;
  }
  // final FC: fp32 out + bias, no relu
  dim3 gf(MB, 1);
  hgemm<float><<<gf, 256, 0, stream>>>(h, wH[6], (float*)d_out, N, 128, 128, nullptr, fc_b);
}

// Round 5
// 1177.714 us; speedup vs baseline: 1.6697x; 1.0125x over previous
//
#include <hip/hip_runtime.h>
#include <cstddef>
#include <cstdint>

// ---------------------------------------------------------------------------
// N=50000 nodes, E=1,650,000 edges (incl. self loops). Stages (in,out):
// (512,384),(384,256),(256,128), FC 128->128.
// Pipeline (all activations/weights fp16, accumulation fp32):
//   convert -> [per stage: MFMA GEMM -> CSR agg] x6 -> MFMA FC (fp32 out)
// GEMM-first restructuring: (A h) W^T == A (h W^T); row scales commute.
// R4 (resubmit; previous run died to container infra, no test verdict):
//     CSR build fully atomic-free: dst-histogram's LDS atomicAdd return value
//     IS the within-(chunk,node) ordinal; chunk-axis scan gives bases; scatter
//     stages its base row in LDS. Zero global RMWs. Agg grid = 2 tiles/block
//     (1563 blocks, one dispatch round) to flatten the occupancy tail.
// Agg wall evidence (R1/R2/R3): dur scales linearly with D (bytes) and is
// insensitive to ILP and working-set size -> ~7 TB/s random-gather wall.
// ---------------------------------------------------------------------------

typedef _Float16 h8 __attribute__((ext_vector_type(8)));
typedef _Float16 h4 __attribute__((ext_vector_type(4)));
typedef float f32x4 __attribute__((ext_vector_type(4)));

#define HB 64    // src-histogram blocks
#define NCH 256  // dst chunks (per-chunk count <= E/256 = 6446 < 65536)

// ---------------- degree / CSR build (no global atomics) ----------------

// dst histogram per chunk + edge ordinals. LDS atomicAdd's returned old value
// is a unique within-(chunk,node) ordinal (order-freedom is fine: CSR rows may
// hold sources in any permutation for a sum aggregator).
__global__ __launch_bounds__(1024) void histo_dst_kernel(
    const int* __restrict__ dst, uint32_t* __restrict__ H,
    int* __restrict__ ord, int E, int bins2, int CE) {
  __shared__ uint32_t hh[25088];  // 100 KB, 2 x u16 bins per u32
  for (int i = threadIdx.x; i < bins2; i += 1024) hh[i] = 0;
  __syncthreads();
  const int base = blockIdx.x * CE;
  int lim = base + CE; if (lim > E) lim = E;
  for (int e = base + (int)threadIdx.x; e < lim; e += 1024) {
    int d = dst[e];
    const int sh = (d & 1) * 16;
    uint32_t old = atomicAdd(&hh[d >> 1], 1u << sh);
    ord[e] = (int)((old >> sh) & 0xFFFFu);
  }
  __syncthreads();
  uint32_t* out = H + (size_t)blockIdx.x * bins2;
  for (int i = threadIdx.x; i < bins2; i += 1024) out[i] = hh[i];
}

// src (out-degree) histogram: 64 blocks, packed u16 bins (<= E/64 = 25782).
__global__ __launch_bounds__(1024) void histo_out_kernel(
    const int* __restrict__ src, uint32_t* __restrict__ H, int E, int bins2) {
  __shared__ uint32_t hh[25088];
  for (int i = threadIdx.x; i < bins2; i += 1024) hh[i] = 0;
  __syncthreads();
  const int C = (E + HB - 1) / HB;
  const int base = blockIdx.x * C;
  int lim = base + C; if (lim > E) lim = E;
  for (int e = base + (int)threadIdx.x; e < lim; e += 1024) {
    int s = src[e];
    atomicAdd(&hh[s >> 1], 1u << ((s & 1) * 16));
  }
  __syncthreads();
  uint32_t* out = H + (size_t)blockIdx.x * bins2;
  for (int i = threadIdx.x; i < bins2; i += 1024) out[i] = hh[i];
}

__global__ __launch_bounds__(256) void reduce_out_kernel(
    const uint32_t* __restrict__ H, int* __restrict__ out_deg,
    int bins2, int n) {
  int i = blockIdx.x * 256 + threadIdx.x;
  if (i >= bins2) return;
  uint32_t lo = 0, hi = 0;
  for (int b = 0; b < HB; ++b) {
    uint32_t v = H[(size_t)b * bins2 + i];
    lo += v & 0xFFFFu;
    hi += v >> 16;
  }
  out_deg[2 * i] = (int)lo;
  if (2 * i + 1 < n) out_deg[2 * i + 1] = (int)hi;
}

// in-place exclusive scan of H along the chunk axis (packed u16 lanes);
// emits in-degree totals. Column-major walk -> fully coalesced.
__global__ __launch_bounds__(256) void chunk_scan_kernel(
    uint32_t* __restrict__ H, int* __restrict__ in_deg, int bins2, int n) {
  int i = blockIdx.x * 256 + threadIdx.x;
  if (i >= bins2) return;
  uint32_t lo = 0, hi = 0;
  for (int c = 0; c < NCH; ++c) {
    uint32_t* p = H + (size_t)c * bins2 + i;
    uint32_t v = *p;
    *p = lo | (hi << 16);   // exclusive base (max degree << 65536)
    lo += v & 0xFFFFu;
    hi += v >> 16;
  }
  in_deg[2 * i] = (int)lo;
  if (2 * i + 1 < n) in_deg[2 * i + 1] = (int)hi;
}

// ---- 3-phase scan of in_deg -> row_ptr (nb <= 256 blocks of 256) ----

__global__ __launch_bounds__(256) void scan_a(
    const int* __restrict__ deg, int* __restrict__ bsum, int n) {
  __shared__ int s[256];
  int i = blockIdx.x * 256 + threadIdx.x;
  s[threadIdx.x] = (i < n) ? deg[i] : 0;
  __syncthreads();
  #pragma unroll
  for (int off = 128; off > 0; off >>= 1) {
    if ((int)threadIdx.x < off) s[threadIdx.x] += s[threadIdx.x + off];
    __syncthreads();
  }
  if (threadIdx.x == 0) bsum[blockIdx.x] = s[0];
}

__global__ __launch_bounds__(256) void scan_b(
    int* __restrict__ bsum, int* __restrict__ rp, int nb, int n) {
  __shared__ int s[256];
  const int t = threadIdx.x;
  int v = (t < nb) ? bsum[t] : 0;
  s[t] = v;
  __syncthreads();
  #pragma unroll
  for (int off = 1; off < 256; off <<= 1) {
    int a = (t >= off) ? s[t - off] : 0;
    __syncthreads();
    s[t] += a;
    __syncthreads();
  }
  bsum[256 + t] = s[t] - v;  // exclusive block offset
  if (t == 255) rp[n] = s[255];
}

// block-local scan + write row_ptr; degree scalers fused.
__global__ __launch_bounds__(256) void scan_c(
    const int* __restrict__ in_deg, const int* __restrict__ out_deg,
    const int* __restrict__ bsum, int* __restrict__ rp,
    float* __restrict__ inv_src, float* __restrict__ inv_dst,
    float* __restrict__ inv_den, int n) {
  __shared__ int s[256];
  const int t = threadIdx.x;
  const int i = blockIdx.x * 256 + t;
  int v = (i < n) ? in_deg[i] : 0;
  s[t] = v;
  __syncthreads();
  #pragma unroll
  for (int off = 1; off < 256; off <<= 1) {
    int a = (t >= off) ? s[t - off] : 0;
    __syncthreads();
    s[t] += a;
    __syncthreads();
  }
  if (i < n) {
    rp[i] = bsum[256 + blockIdx.x] + s[t] - v;
    float od = (float)out_deg[i];
    float id = (float)v;
    inv_src[i] = rsqrtf(od > 0.f ? od : 1.0f);
    inv_dst[i] = rsqrtf(id > 0.f ? id : 1.0f);
    inv_den[i] = 1.0f / (id + 1.0f);
  }
}

// atomic-free scatter: block c stages its (scanned) base row in LDS, then
// csr[rp[d] + base[c][d] + ord[e]] = src[e].
__global__ __launch_bounds__(1024) void scatter_kernel(
    const int* __restrict__ src, const int* __restrict__ dst,
    const int* __restrict__ rp, const int* __restrict__ ord,
    const uint32_t* __restrict__ H, int* __restrict__ csr,
    int E, int bins2, int CE) {
  __shared__ uint32_t hh[25088];
  const uint32_t* Hc = H + (size_t)blockIdx.x * bins2;
  for (int i = threadIdx.x; i < bins2; i += 1024) hh[i] = Hc[i];
  __syncthreads();
  const int base = blockIdx.x * CE;
  int lim = base + CE; if (lim > E) lim = E;
  for (int e = base + (int)threadIdx.x; e < lim; e += 1024) {
    int d = dst[e];
    int b = (int)((hh[d >> 1] >> ((d & 1) * 16)) & 0xFFFFu);
    csr[rp[d] + b + ord[e]] = src[e];
  }
}

// ---------------- fp32 -> fp16 conversion ----------------

__global__ __launch_bounds__(256) void cvt_kernel(
    const float* __restrict__ in, _Float16* __restrict__ out,
    long n_in, long n_pad) {
  long i = ((long)blockIdx.x * 256 + (long)threadIdx.x) * 4;
  if (i >= n_pad) return;
  float4 v = (i < n_in) ? *(const float4*)(in + i) : make_float4(0.f, 0.f, 0.f, 0.f);
  h4 h = {(_Float16)v.x, (_Float16)v.y, (_Float16)v.z, (_Float16)v.w};
  *(h4*)(out + i) = h;
}

// all 7 weight conversions in one launch (sizes all multiples of 4)
struct WArgs {
  const float* s[7];
  _Float16* d[7];
  int n[7];
};

__global__ __launch_bounds__(256) void wcvt_kernel(WArgs a) {
  const int w = blockIdx.y;
  long i = ((long)blockIdx.x * 256 + (long)threadIdx.x) * 4;
  if (i >= a.n[w]) return;
  float4 v = *(const float4*)(a.s[w] + i);
  h4 h = {(_Float16)v.x, (_Float16)v.y, (_Float16)v.z, (_Float16)v.w};
  *(h4*)(a.d[w] + i) = h;
}

// ---------------- async global->LDS helper (width=16, literal per guide) ----

__device__ __forceinline__ void gload_lds16(const _Float16* g, _Float16* l) {
  __builtin_amdgcn_global_load_lds(
      (const __attribute__((address_space(1))) void*)g,
      (__attribute__((address_space(3))) void*)l, 16, 0, 0);
}

// ---------------- fp16 MFMA GEMM: C[M x Nc] = A[M x K] @ W^T ----------------
// A padded to a multiple of 128 rows (pad rows hold finite junk; their C rows
// are discarded by the m<Mstore store guard). W row-major [Nc x K]. Epilogue:
// optional per-row scale + bias. 256 thr = 4 waves (2x2), 64x64/wave,
// 16x16x32_f16 MFMA, BK=32, LDS 2x8KB. Staging via global_load_lds width=16:
// LDS byte offset == tid*16 (linear in lane order as HW requires).
// Fragment layouts (HW-verified, guide §3): A/B lane l: idx=l&15, k=(l>>4)*8+j;
// C/D lane l: col=l&15, row=(l>>4)*4+reg.

template <typename OutT>
__global__ __launch_bounds__(256) void hgemm(
    const _Float16* __restrict__ A, const _Float16* __restrict__ W,
    OutT* __restrict__ C, int Mstore, int K, int Nc,
    const float* __restrict__ row_scale, const float* __restrict__ bias) {
  __shared__ _Float16 As[128 * 32];
  __shared__ _Float16 Bs[128 * 32];
  const int tid = threadIdx.x;
  const int bm = blockIdx.x * 128, bn = blockIdx.y * 128;
  const int wave = tid >> 6, lane = tid & 63;
  const int wm = (wave & 1) * 64, wn = (wave >> 1) * 64;
  const int lrow = lane & 15, lq = lane >> 4;

  const int r0 = tid >> 2;
  const int cc = (tid & 3) * 8;
  const _Float16* Ag = A + (size_t)(bm + r0) * K + cc;
  const _Float16* Wg = W + (size_t)(bn + r0) * K + cc;
  const size_t rs64 = (size_t)64 * K;
  _Float16* As0 = As + tid * 8;
  _Float16* As1 = As + 64 * 32 + tid * 8;
  _Float16* Bs0 = Bs + tid * 8;
  _Float16* Bs1 = Bs + 64 * 32 + tid * 8;

  f32x4 acc[4][4];
  #pragma unroll
  for (int i = 0; i < 4; ++i)
    #pragma unroll
    for (int j = 0; j < 4; ++j) acc[i][j] = (f32x4){0.f, 0.f, 0.f, 0.f};

  for (int k0 = 0; k0 < K; k0 += 32) {
    __syncthreads();  // previous tile's ds_reads complete before overwrite
    gload_lds16(Ag + k0, As0);
    gload_lds16(Ag + rs64 + k0, As1);
    gload_lds16(Wg + k0, Bs0);
    gload_lds16(Wg + rs64 + k0, Bs1);
    __syncthreads();  // vmcnt(0) drained before s_barrier -> LDS ready
    h8 af[4], bf[4];
    #pragma unroll
    for (int i = 0; i < 4; ++i)
      af[i] = *(const h8*)(As + (wm + i * 16 + lrow) * 32 + lq * 8);
    #pragma unroll
    for (int j = 0; j < 4; ++j)
      bf[j] = *(const h8*)(Bs + (wn + j * 16 + lrow) * 32 + lq * 8);
    #pragma unroll
    for (int i = 0; i < 4; ++i)
      #pragma unroll
      for (int j = 0; j < 4; ++j)
        acc[i][j] = __builtin_amdgcn_mfma_f32_16x16x32_f16(af[i], bf[j], acc[i][j], 0, 0, 0);
  }

  #pragma unroll
  for (int i = 0; i < 4; ++i) {
    #pragma unroll
    for (int r = 0; r < 4; ++r) {
      const int m = bm + wm + i * 16 + lq * 4 + r;
      if (m < Mstore) {
        const float rsc = row_scale ? row_scale[m] : 1.0f;
        OutT* crow = C + (size_t)m * Nc + bn + wn + lrow;
        #pragma unroll
        for (int j = 0; j < 4; ++j) {
          float v = acc[i][j][r] * rsc;
          if (bias) v += bias[bn + wn + j * 16 + lrow];
          crow[j * 16] = (OutT)v;
        }
      }
    }
  }
}

// ---------------- CSR aggregation, fp16 gather / fp32 accumulate ----------------
// out[n] = relu(((sum_{e:dst=n} Z[csr[e]]) (+ Z[n] if SELF)) * out_scale[n] + bias)
// 16 lanes per node; 16B gathers. Evidence (R1-R3): dur linear in gathered
// bytes, insensitive to ILP and working-set size -> ~7 TB/s gather wall.
// R4: 2 node-tiles per block (grid 1563 = 6.1 blocks/CU, one dispatch round)
// to flatten the 8+4-round occupancy tail of the 3125-block version.

template <int D, bool SELF>
__global__ __launch_bounds__(256) void agg_h(
    const _Float16* __restrict__ Z, const int* __restrict__ row_ptr,
    const int* __restrict__ csr, const float* __restrict__ out_scale,
    const float* __restrict__ bias, _Float16* __restrict__ out, int n) {
  constexpr int CH = D / 8;       // 16B chunks per row (48/32/16)
  constexpr int GROUP = 16;
  constexpr int NV = CH / GROUP;  // 3/2/1 chunks per lane
  const int gid = threadIdx.x >> 4;
  const int lane = threadIdx.x & 15;
  const int stride = gridDim.x * 16;

  for (int node = blockIdx.x * 16 + gid; node < n; node += stride) {
    const int rs = row_ptr[node], re = row_ptr[node + 1];

    float acc[NV][8];
    #pragma unroll
    for (int v = 0; v < NV; ++v)
      #pragma unroll
      for (int q = 0; q < 8; ++q) acc[v][q] = 0.f;

    for (int e = rs; e < re; e += GROUP) {
      int m = re - e; if (m > GROUP) m = GROUP;
      int eid = (lane < m) ? csr[e + lane] : 0;
      for (int j = 0; j < m; ++j) {
        int s = __shfl(eid, j, GROUP);
        const h8* zr = (const h8*)(Z + (size_t)s * D);
        #pragma unroll
        for (int v = 0; v < NV; ++v) {
          h8 t = zr[lane + v * GROUP];
          #pragma unroll
          for (int q = 0; q < 8; ++q) acc[v][q] += (float)t[q];
        }
      }
    }

    const float osc = out_scale[node];
    const h8* zs = (const h8*)(Z + (size_t)node * D);
    _Float16* orow = out + (size_t)node * D;
    #pragma unroll
    for (int v = 0; v < NV; ++v) {
      const int idx = lane + v * GROUP;
      if (SELF) {
        h8 t = zs[idx];
        #pragma unroll
        for (int q = 0; q < 8; ++q) acc[v][q] += (float)t[q];
      }
      h8 r;
      #pragma unroll
      for (int q = 0; q < 8; ++q) {
        float x = acc[v][q] * osc + bias[idx * 8 + q];
        r[q] = (_Float16)fmaxf(x, 0.f);
      }
      *(h8*)(orow + idx * 8) = r;
    }
  }
}

// ---------------- host-side orchestration ----------------

extern "C" void kernel_launch(void* const* d_in, const int* in_sizes, int n_in,
                              void* d_out, int out_size, void* d_ws, size_t ws_size,
                              hipStream_t stream) {
  const float* features = (const float*)d_in[0];
  const int*   src      = (const int*)d_in[1];
  const int*   dst      = (const int*)d_in[2];
  const float* wsrc[7] = {(const float*)d_in[3],  (const float*)d_in[5],
                          (const float*)d_in[7],  (const float*)d_in[9],
                          (const float*)d_in[11], (const float*)d_in[13],
                          (const float*)d_in[15]};  // sw0,gw0,sw1,gw1,sw2,gw2,fc
  const float* sb[3] = {(const float*)d_in[4],  (const float*)d_in[8],  (const float*)d_in[12]};
  const float* gb[3] = {(const float*)d_in[6],  (const float*)d_in[10], (const float*)d_in[14]};
  const float* fc_b  = (const float*)d_in[16];

  const int N = in_sizes[0] / 512;
  const int E = in_sizes[1];
  const int MB = (N + 127) / 128;
  const int Mpad = MB * 128;
  const int bins2 = (N + 1) / 2;
  if (bins2 > 25088) return;  // LDS histogram capacity

  const int wcnt[7] = {384 * 512, 384 * 384, 256 * 384, 256 * 256,
                       128 * 256, 128 * 128, 128 * 128};

  // workspace layout (fp16 buffers first, 16B-aligned throughout)
  char* ws = (char*)d_ws;
  _Float16* featH = (_Float16*)ws;                       // Mpad*512
  _Float16* hA    = featH + (size_t)Mpad * 512;          // Mpad*384 (activations)
  _Float16* hB    = hA + (size_t)Mpad * 384;             // Mpad*384 (Z)
  _Float16* wH[7];
  {
    _Float16* p = hB + (size_t)Mpad * 384;
    for (int i = 0; i < 7; ++i) { wH[i] = p; p += wcnt[i]; }
  }
  int* csr     = (int*)(wH[6] + wcnt[6]);                // E ints
  int* rp      = csr + E;                                // N+1
  int* in_dg   = rp + (N + 1);                           // N
  int* out_dg  = in_dg + N;                              // N
  int* sblk    = out_dg + N;                             // N (scan scratch, needs 512)
  float* inv_src = (float*)(sblk + N);                   // N
  float* inv_dst = inv_src + N;                          // N
  float* inv_den = inv_dst + N;                          // N

  // CSR-build scratch aliased into hA/hB (all consumed before the first GEMM
  // writes hB and before the first agg writes hA, in stream order):
  //   hB: ord (E ints, 6.6 MB) + H_src (HB*bins2 u32, 6.4 MB)  <= 38 MB
  //   hA: H_dst (NCH*bins2 u32, 25.6 MB)                        <= 38 MB
  int*      ord  = (int*)hB;
  uint32_t* Hsrc = (uint32_t*)(ord + E);
  uint32_t* Hdst = (uint32_t*)hA;

  size_t totw = 0; for (int i = 0; i < 7; ++i) totw += wcnt[i];
  size_t needed = ((size_t)Mpad * (512 + 384 + 384) + totw) * 2 +
                  ((size_t)E + (N + 1) + 6 * (size_t)N) * 4;
  if (ws_size < needed) return;

  const int CE = (E + NCH - 1) / NCH;
  const int nb256 = (N + 255) / 256;   // <= 256 for N <= 65536
  const int binsb = (bins2 + 255) / 256;

  histo_dst_kernel<<<NCH, 1024, 0, stream>>>(dst, Hdst, ord, E, bins2, CE);
  histo_out_kernel<<<HB, 1024, 0, stream>>>(src, Hsrc, E, bins2);
  chunk_scan_kernel<<<binsb, 256, 0, stream>>>(Hdst, in_dg, bins2, N);
  reduce_out_kernel<<<binsb, 256, 0, stream>>>(Hsrc, out_dg, bins2, N);
  scan_a<<<nb256, 256, 0, stream>>>(in_dg, sblk, N);
  scan_b<<<1, 256, 0, stream>>>(sblk, rp, nb256, N);
  scan_c<<<nb256, 256, 0, stream>>>(in_dg, out_dg, sblk, rp,
                                    inv_src, inv_dst, inv_den, N);
  scatter_kernel<<<NCH, 1024, 0, stream>>>(src, dst, rp, ord, Hdst, csr,
                                           E, bins2, CE);

  // conversions (featH is independent of the hA/hB-aliased scratch)
  {
    long thr = (long)Mpad * 512 / 4;
    cvt_kernel<<<(int)((thr + 255) / 256), 256, 0, stream>>>(
        features, featH, (long)N * 512, (long)Mpad * 512);
    WArgs wa;
    int maxn = 0;
    for (int i = 0; i < 7; ++i) {
      wa.s[i] = wsrc[i]; wa.d[i] = wH[i]; wa.n[i] = wcnt[i];
      if (wcnt[i] > maxn) maxn = wcnt[i];
    }
    dim3 wg((maxn / 4 + 255) / 256, 7);
    wcvt_kernel<<<wg, 256, 0, stream>>>(wa);
  }

  const int dout[3] = {384, 256, 128};
  const _Float16* h = featH;
  int K = 512;
  const int ab = (N + 31) / 32;  // 2 node-tiles per block, one dispatch round
  for (int s = 0; s < 3; ++s) {
    const int D = dout[s];
    dim3 gg(MB, D / 128);
    // SAGE: Z = h @ sw^T ; h' = relu((sum_in Z + Z_self)*inv_den + sb)
    hgemm<_Float16><<<gg, 256, 0, stream>>>(h, wH[2 * s], hB, Mpad, K, D, nullptr, nullptr);
    if (D == 384)      agg_h<384, true><<<ab, 256, 0, stream>>>(hB, rp, csr, inv_den, sb[s], hA, N);
    else if (D == 256) agg_h<256, true><<<ab, 256, 0, stream>>>(hB, rp, csr, inv_den, sb[s], hA, N);
    else               agg_h<128, true><<<ab, 256, 0, stream>>>(hB, rp, csr, inv_den, sb[s], hA, N);
    // GraphConv: Z = (h'*inv_src) @ gw^T ; h'' = relu((sum_in Z)*inv_dst + gb)
    hgemm<_Float16><<<gg, 256, 0, stream>>>(hA, wH[2 * s + 1], hB, Mpad, D, D, inv_src, nullptr);
    if (D == 384)      agg_h<384, false><<<ab, 256, 0, stream>>>(hB, rp, csr, inv_dst, gb[s], hA, N);
    else if (D == 256) agg_h<256, false><<<ab, 256, 0, stream>>>(hB, rp, csr, inv_dst, gb[s], hA, N);
    else               agg_h<128, false><<<ab, 256, 0, stream>>>(hB, rp, csr, inv_dst, gb[s], hA, N);
    h = hA;
    K = D;
  }
  // final FC: fp32 out + bias, no relu
  dim3 gf(MB, 1);
  hgemm<float><<<gf, 256, 0, stream>>>(h, wH[6], (float*)d_out, N, 128, 128, nullptr, fc_b);
}

// Round 6
// 1171.271 us; speedup vs baseline: 1.6789x; 1.0055x over previous
//
#include <hip/hip_runtime.h>
#include <cstddef>
#include <cstdint>

// ---------------------------------------------------------------------------
// N=50000 nodes, E=1,650,000 edges (incl. self loops). Stages (in,out):
// (512,384),(384,256),(256,128), FC 128->128.
// Pipeline (all activations/weights fp16, accumulation fp32):
//   convert -> [per stage: MFMA GEMM -> CSR agg] x6 -> MFMA FC (fp32 out)
// GEMM-first restructuring: (A h) W^T == A (h W^T); row scales commute.
// R6: hgemm 2-phase software pipeline (double-buffered LDS, STAGE(t+1) issued
//     BEFORE compute of tile t, single barrier per iter -> staging latency
//     overlaps MFMA; barriers halved). reduce_out fused into chunk_scan.
//     agg kernels byte-identical to R4 (confirmed memory-wall: ~7 TB/s
//     logical / 3.2 TB/s L2-miss, insensitive to ILP/occupancy/panels).
// ---------------------------------------------------------------------------

typedef _Float16 h8 __attribute__((ext_vector_type(8)));
typedef _Float16 h4 __attribute__((ext_vector_type(4)));
typedef float f32x4 __attribute__((ext_vector_type(4)));

#define HB 64    // src-histogram blocks
#define NCH 256  // dst chunks (per-chunk count <= E/256 = 6446 < 65536)

// ---------------- degree / CSR build (no global atomics) ----------------

// dst histogram per chunk + edge ordinals. LDS atomicAdd's returned old value
// is a unique within-(chunk,node) ordinal (order-freedom is fine: CSR rows may
// hold sources in any permutation for a sum aggregator).
__global__ __launch_bounds__(1024) void histo_dst_kernel(
    const int* __restrict__ dst, uint32_t* __restrict__ H,
    int* __restrict__ ord, int E, int bins2, int CE) {
  __shared__ uint32_t hh[25088];  // 100 KB, 2 x u16 bins per u32
  for (int i = threadIdx.x; i < bins2; i += 1024) hh[i] = 0;
  __syncthreads();
  const int base = blockIdx.x * CE;
  int lim = base + CE; if (lim > E) lim = E;
  for (int e = base + (int)threadIdx.x; e < lim; e += 1024) {
    int d = dst[e];
    const int sh = (d & 1) * 16;
    uint32_t old = atomicAdd(&hh[d >> 1], 1u << sh);
    ord[e] = (int)((old >> sh) & 0xFFFFu);
  }
  __syncthreads();
  uint32_t* out = H + (size_t)blockIdx.x * bins2;
  for (int i = threadIdx.x; i < bins2; i += 1024) out[i] = hh[i];
}

// src (out-degree) histogram: 64 blocks, packed u16 bins (<= E/64 = 25782).
__global__ __launch_bounds__(1024) void histo_out_kernel(
    const int* __restrict__ src, uint32_t* __restrict__ H, int E, int bins2) {
  __shared__ uint32_t hh[25088];
  for (int i = threadIdx.x; i < bins2; i += 1024) hh[i] = 0;
  __syncthreads();
  const int C = (E + HB - 1) / HB;
  const int base = blockIdx.x * C;
  int lim = base + C; if (lim > E) lim = E;
  for (int e = base + (int)threadIdx.x; e < lim; e += 1024) {
    int s = src[e];
    atomicAdd(&hh[s >> 1], 1u << ((s & 1) * 16));
  }
  __syncthreads();
  uint32_t* out = H + (size_t)blockIdx.x * bins2;
  for (int i = threadIdx.x; i < bins2; i += 1024) out[i] = hh[i];
}

// in-place exclusive scan of Hdst along the chunk axis (packed u16 lanes) ->
// per-chunk bases + in-degree totals; fused sum of Hsrc -> out-degree.
__global__ __launch_bounds__(256) void chunk_scan_kernel(
    uint32_t* __restrict__ Hd, const uint32_t* __restrict__ Hs,
    int* __restrict__ in_deg, int* __restrict__ out_deg, int bins2, int n) {
  int i = blockIdx.x * 256 + threadIdx.x;
  if (i >= bins2) return;
  uint32_t lo = 0, hi = 0;
  for (int c = 0; c < NCH; ++c) {
    uint32_t* p = Hd + (size_t)c * bins2 + i;
    uint32_t v = *p;
    *p = lo | (hi << 16);   // exclusive base (max degree << 65536)
    lo += v & 0xFFFFu;
    hi += v >> 16;
  }
  in_deg[2 * i] = (int)lo;
  if (2 * i + 1 < n) in_deg[2 * i + 1] = (int)hi;
  uint32_t slo = 0, shi = 0;
  for (int b = 0; b < HB; ++b) {
    uint32_t v = Hs[(size_t)b * bins2 + i];
    slo += v & 0xFFFFu;
    shi += v >> 16;
  }
  out_deg[2 * i] = (int)slo;
  if (2 * i + 1 < n) out_deg[2 * i + 1] = (int)shi;
}

// ---- 3-phase scan of in_deg -> row_ptr (nb <= 256 blocks of 256) ----

__global__ __launch_bounds__(256) void scan_a(
    const int* __restrict__ deg, int* __restrict__ bsum, int n) {
  __shared__ int s[256];
  int i = blockIdx.x * 256 + threadIdx.x;
  s[threadIdx.x] = (i < n) ? deg[i] : 0;
  __syncthreads();
  #pragma unroll
  for (int off = 128; off > 0; off >>= 1) {
    if ((int)threadIdx.x < off) s[threadIdx.x] += s[threadIdx.x + off];
    __syncthreads();
  }
  if (threadIdx.x == 0) bsum[blockIdx.x] = s[0];
}

__global__ __launch_bounds__(256) void scan_b(
    int* __restrict__ bsum, int* __restrict__ rp, int nb, int n) {
  __shared__ int s[256];
  const int t = threadIdx.x;
  int v = (t < nb) ? bsum[t] : 0;
  s[t] = v;
  __syncthreads();
  #pragma unroll
  for (int off = 1; off < 256; off <<= 1) {
    int a = (t >= off) ? s[t - off] : 0;
    __syncthreads();
    s[t] += a;
    __syncthreads();
  }
  bsum[256 + t] = s[t] - v;  // exclusive block offset
  if (t == 255) rp[n] = s[255];
}

// block-local scan + write row_ptr; degree scalers fused.
__global__ __launch_bounds__(256) void scan_c(
    const int* __restrict__ in_deg, const int* __restrict__ out_deg,
    const int* __restrict__ bsum, int* __restrict__ rp,
    float* __restrict__ inv_src, float* __restrict__ inv_dst,
    float* __restrict__ inv_den, int n) {
  __shared__ int s[256];
  const int t = threadIdx.x;
  const int i = blockIdx.x * 256 + t;
  int v = (i < n) ? in_deg[i] : 0;
  s[t] = v;
  __syncthreads();
  #pragma unroll
  for (int off = 1; off < 256; off <<= 1) {
    int a = (t >= off) ? s[t - off] : 0;
    __syncthreads();
    s[t] += a;
    __syncthreads();
  }
  if (i < n) {
    rp[i] = bsum[256 + blockIdx.x] + s[t] - v;
    float od = (float)out_deg[i];
    float id = (float)v;
    inv_src[i] = rsqrtf(od > 0.f ? od : 1.0f);
    inv_dst[i] = rsqrtf(id > 0.f ? id : 1.0f);
    inv_den[i] = 1.0f / (id + 1.0f);
  }
}

// atomic-free scatter: block c stages its (scanned) base row in LDS, then
// csr[rp[d] + base[c][d] + ord[e]] = src[e].
__global__ __launch_bounds__(1024) void scatter_kernel(
    const int* __restrict__ src, const int* __restrict__ dst,
    const int* __restrict__ rp, const int* __restrict__ ord,
    const uint32_t* __restrict__ H, int* __restrict__ csr,
    int E, int bins2, int CE) {
  __shared__ uint32_t hh[25088];
  const uint32_t* Hc = H + (size_t)blockIdx.x * bins2;
  for (int i = threadIdx.x; i < bins2; i += 1024) hh[i] = Hc[i];
  __syncthreads();
  const int base = blockIdx.x * CE;
  int lim = base + CE; if (lim > E) lim = E;
  for (int e = base + (int)threadIdx.x; e < lim; e += 1024) {
    int d = dst[e];
    int b = (int)((hh[d >> 1] >> ((d & 1) * 16)) & 0xFFFFu);
    csr[rp[d] + b + ord[e]] = src[e];
  }
}

// ---------------- fp32 -> fp16 conversion ----------------

__global__ __launch_bounds__(256) void cvt_kernel(
    const float* __restrict__ in, _Float16* __restrict__ out,
    long n_in, long n_pad) {
  long i = ((long)blockIdx.x * 256 + (long)threadIdx.x) * 4;
  if (i >= n_pad) return;
  float4 v = (i < n_in) ? *(const float4*)(in + i) : make_float4(0.f, 0.f, 0.f, 0.f);
  h4 h = {(_Float16)v.x, (_Float16)v.y, (_Float16)v.z, (_Float16)v.w};
  *(h4*)(out + i) = h;
}

// all 7 weight conversions in one launch (sizes all multiples of 4)
struct WArgs {
  const float* s[7];
  _Float16* d[7];
  int n[7];
};

__global__ __launch_bounds__(256) void wcvt_kernel(WArgs a) {
  const int w = blockIdx.y;
  long i = ((long)blockIdx.x * 256 + (long)threadIdx.x) * 4;
  if (i >= a.n[w]) return;
  float4 v = *(const float4*)(a.s[w] + i);
  h4 h = {(_Float16)v.x, (_Float16)v.y, (_Float16)v.z, (_Float16)v.w};
  *(h4*)(a.d[w] + i) = h;
}

// ---------------- async global->LDS helper (width=16, literal per guide) ----

__device__ __forceinline__ void gload_lds16(const _Float16* g, _Float16* l) {
  __builtin_amdgcn_global_load_lds(
      (const __attribute__((address_space(1))) void*)g,
      (__attribute__((address_space(3))) void*)l, 16, 0, 0);
}

// ---------------- fp16 MFMA GEMM: C[M x Nc] = A[M x K] @ W^T ----------------
// A padded to a multiple of 128 rows (pad rows hold finite junk; their C rows
// are discarded by the m<Mstore store guard). W row-major [Nc x K]. Epilogue:
// optional per-row scale + bias. 256 thr = 4 waves (2x2), 64x64/wave,
// 16x16x32_f16 MFMA, BK=32, LDS 2 x (8+8) KB double-buffered.
// R6 2-phase pipeline: prologue stages tile 0; per iter issue STAGE(t+1) into
// buf^1 BEFORE ds_read/MFMA of buf, then one __syncthreads() (its implicit
// vmcnt(0)+lgkmcnt(0) drains the prefetch AND the ds_reads). Staging latency
// overlaps compute; one barrier per K-step instead of two.
// Staging dest: LDS byte offset == tid*16 (wave-uniform base + lane*16, as
// global_load_lds requires). Fragment layouts (HW-verified, guide §3):
// A/B lane l: idx=l&15, k=(l>>4)*8+j; C/D lane l: col=l&15, row=(l>>4)*4+reg.

template <typename OutT>
__global__ __launch_bounds__(256) void hgemm(
    const _Float16* __restrict__ A, const _Float16* __restrict__ W,
    OutT* __restrict__ C, int Mstore, int K, int Nc,
    const float* __restrict__ row_scale, const float* __restrict__ bias) {
  __shared__ _Float16 As[2][128 * 32];
  __shared__ _Float16 Bs[2][128 * 32];
  const int tid = threadIdx.x;
  const int bm = blockIdx.x * 128, bn = blockIdx.y * 128;
  const int wave = tid >> 6, lane = tid & 63;
  const int wm = (wave & 1) * 64, wn = (wave >> 1) * 64;
  const int lrow = lane & 15, lq = lane >> 4;

  const int r0 = tid >> 2;
  const int cc = (tid & 3) * 8;
  const _Float16* Ag = A + (size_t)(bm + r0) * K + cc;
  const _Float16* Wg = W + (size_t)(bn + r0) * K + cc;
  const size_t rs64 = (size_t)64 * K;
  const int l8 = tid * 8;

  f32x4 acc[4][4];
  #pragma unroll
  for (int i = 0; i < 4; ++i)
    #pragma unroll
    for (int j = 0; j < 4; ++j) acc[i][j] = (f32x4){0.f, 0.f, 0.f, 0.f};

  const int nt = K >> 5;
  // prologue: stage tile 0 into buf 0
  gload_lds16(Ag, As[0] + l8);
  gload_lds16(Ag + rs64, As[0] + 64 * 32 + l8);
  gload_lds16(Wg, Bs[0] + l8);
  gload_lds16(Wg + rs64, Bs[0] + 64 * 32 + l8);
  __syncthreads();

  int cur = 0;
  for (int t = 0; t < nt; ++t) {
    if (t + 1 < nt) {  // issue next tile's stage before computing current
      const int k1 = (t + 1) << 5;
      gload_lds16(Ag + k1, As[cur ^ 1] + l8);
      gload_lds16(Ag + rs64 + k1, As[cur ^ 1] + 64 * 32 + l8);
      gload_lds16(Wg + k1, Bs[cur ^ 1] + l8);
      gload_lds16(Wg + rs64 + k1, Bs[cur ^ 1] + 64 * 32 + l8);
    }
    h8 af[4], bf[4];
    #pragma unroll
    for (int i = 0; i < 4; ++i)
      af[i] = *(const h8*)(As[cur] + (wm + i * 16 + lrow) * 32 + lq * 8);
    #pragma unroll
    for (int j = 0; j < 4; ++j)
      bf[j] = *(const h8*)(Bs[cur] + (wn + j * 16 + lrow) * 32 + lq * 8);
    #pragma unroll
    for (int i = 0; i < 4; ++i)
      #pragma unroll
      for (int j = 0; j < 4; ++j)
        acc[i][j] = __builtin_amdgcn_mfma_f32_16x16x32_f16(af[i], bf[j], acc[i][j], 0, 0, 0);
    __syncthreads();  // drains prefetch (vmcnt) + all waves' ds_reads (lgkm)
    cur ^= 1;
  }

  #pragma unroll
  for (int i = 0; i < 4; ++i) {
    #pragma unroll
    for (int r = 0; r < 4; ++r) {
      const int m = bm + wm + i * 16 + lq * 4 + r;
      if (m < Mstore) {
        const float rsc = row_scale ? row_scale[m] : 1.0f;
        OutT* crow = C + (size_t)m * Nc + bn + wn + lrow;
        #pragma unroll
        for (int j = 0; j < 4; ++j) {
          float v = acc[i][j][r] * rsc;
          if (bias) v += bias[bn + wn + j * 16 + lrow];
          crow[j * 16] = (OutT)v;
        }
      }
    }
  }
}

// ---------------- CSR aggregation, fp16 gather / fp32 accumulate ----------------
// out[n] = relu(((sum_{e:dst=n} Z[csr[e]]) (+ Z[n] if SELF)) * out_scale[n] + bias)
// 16 lanes per node; 16B gathers. Evidence (R1-R5): dur linear in gathered
// bytes, insensitive to ILP, working-set size, and occupancy -> memory-system
// throughput wall (~7 TB/s logical / ~3.2 TB/s L2-miss). Byte-identical to R4.

template <int D, bool SELF>
__global__ __launch_bounds__(256) void agg_h(
    const _Float16* __restrict__ Z, const int* __restrict__ row_ptr,
    const int* __restrict__ csr, const float* __restrict__ out_scale,
    const float* __restrict__ bias, _Float16* __restrict__ out, int n) {
  constexpr int CH = D / 8;       // 16B chunks per row (48/32/16)
  constexpr int GROUP = 16;
  constexpr int NV = CH / GROUP;  // 3/2/1 chunks per lane
  const int gid = threadIdx.x >> 4;
  const int lane = threadIdx.x & 15;
  const int stride = gridDim.x * 16;

  for (int node = blockIdx.x * 16 + gid; node < n; node += stride) {
    const int rs = row_ptr[node], re = row_ptr[node + 1];

    float acc[NV][8];
    #pragma unroll
    for (int v = 0; v < NV; ++v)
      #pragma unroll
      for (int q = 0; q < 8; ++q) acc[v][q] = 0.f;

    for (int e = rs; e < re; e += GROUP) {
      int m = re - e; if (m > GROUP) m = GROUP;
      int eid = (lane < m) ? csr[e + lane] : 0;
      for (int j = 0; j < m; ++j) {
        int s = __shfl(eid, j, GROUP);
        const h8* zr = (const h8*)(Z + (size_t)s * D);
        #pragma unroll
        for (int v = 0; v < NV; ++v) {
          h8 t = zr[lane + v * GROUP];
          #pragma unroll
          for (int q = 0; q < 8; ++q) acc[v][q] += (float)t[q];
        }
      }
    }

    const float osc = out_scale[node];
    const h8* zs = (const h8*)(Z + (size_t)node * D);
    _Float16* orow = out + (size_t)node * D;
    #pragma unroll
    for (int v = 0; v < NV; ++v) {
      const int idx = lane + v * GROUP;
      if (SELF) {
        h8 t = zs[idx];
        #pragma unroll
        for (int q = 0; q < 8; ++q) acc[v][q] += (float)t[q];
      }
      h8 r;
      #pragma unroll
      for (int q = 0; q < 8; ++q) {
        float x = acc[v][q] * osc + bias[idx * 8 + q];
        r[q] = (_Float16)fmaxf(x, 0.f);
      }
      *(h8*)(orow + idx * 8) = r;
    }
  }
}

// ---------------- host-side orchestration ----------------

extern "C" void kernel_launch(void* const* d_in, const int* in_sizes, int n_in,
                              void* d_out, int out_size, void* d_ws, size_t ws_size,
                              hipStream_t stream) {
  const float* features = (const float*)d_in[0];
  const int*   src      = (const int*)d_in[1];
  const int*   dst      = (const int*)d_in[2];
  const float* wsrc[7] = {(const float*)d_in[3],  (const float*)d_in[5],
                          (const float*)d_in[7],  (const float*)d_in[9],
                          (const float*)d_in[11], (const float*)d_in[13],
                          (const float*)d_in[15]};  // sw0,gw0,sw1,gw1,sw2,gw2,fc
  const float* sb[3] = {(const float*)d_in[4],  (const float*)d_in[8],  (const float*)d_in[12]};
  const float* gb[3] = {(const float*)d_in[6],  (const float*)d_in[10], (const float*)d_in[14]};
  const float* fc_b  = (const float*)d_in[16];

  const int N = in_sizes[0] / 512;
  const int E = in_sizes[1];
  const int MB = (N + 127) / 128;
  const int Mpad = MB * 128;
  const int bins2 = (N + 1) / 2;
  if (bins2 > 25088) return;  // LDS histogram capacity

  const int wcnt[7] = {384 * 512, 384 * 384, 256 * 384, 256 * 256,
                       128 * 256, 128 * 128, 128 * 128};

  // workspace layout (fp16 buffers first, 16B-aligned throughout)
  char* ws = (char*)d_ws;
  _Float16* featH = (_Float16*)ws;                       // Mpad*512
  _Float16* hA    = featH + (size_t)Mpad * 512;          // Mpad*384 (activations)
  _Float16* hB    = hA + (size_t)Mpad * 384;             // Mpad*384 (Z)
  _Float16* wH[7];
  {
    _Float16* p = hB + (size_t)Mpad * 384;
    for (int i = 0; i < 7; ++i) { wH[i] = p; p += wcnt[i]; }
  }
  int* csr     = (int*)(wH[6] + wcnt[6]);                // E ints
  int* rp      = csr + E;                                // N+1
  int* in_dg   = rp + (N + 1);                           // N
  int* out_dg  = in_dg + N;                              // N
  int* sblk    = out_dg + N;                             // N (scan scratch, needs 512)
  float* inv_src = (float*)(sblk + N);                   // N
  float* inv_dst = inv_src + N;                          // N
  float* inv_den = inv_dst + N;                          // N

  // CSR-build scratch aliased into hA/hB (all consumed before the first GEMM
  // writes hB and before the first agg writes hA, in stream order):
  //   hB: ord (E ints, 6.6 MB) + H_src (HB*bins2 u32, 6.4 MB)  <= 38 MB
  //   hA: H_dst (NCH*bins2 u32, 25.6 MB)                        <= 38 MB
  int*      ord  = (int*)hB;
  uint32_t* Hsrc = (uint32_t*)(ord + E);
  uint32_t* Hdst = (uint32_t*)hA;

  size_t totw = 0; for (int i = 0; i < 7; ++i) totw += wcnt[i];
  size_t needed = ((size_t)Mpad * (512 + 384 + 384) + totw) * 2 +
                  ((size_t)E + (N + 1) + 6 * (size_t)N) * 4;
  if (ws_size < needed) return;

  const int CE = (E + NCH - 1) / NCH;
  const int nb256 = (N + 255) / 256;   // <= 256 for N <= 65536
  const int binsb = (bins2 + 255) / 256;

  histo_dst_kernel<<<NCH, 1024, 0, stream>>>(dst, Hdst, ord, E, bins2, CE);
  histo_out_kernel<<<HB, 1024, 0, stream>>>(src, Hsrc, E, bins2);
  chunk_scan_kernel<<<binsb, 256, 0, stream>>>(Hdst, Hsrc, in_dg, out_dg, bins2, N);
  scan_a<<<nb256, 256, 0, stream>>>(in_dg, sblk, N);
  scan_b<<<1, 256, 0, stream>>>(sblk, rp, nb256, N);
  scan_c<<<nb256, 256, 0, stream>>>(in_dg, out_dg, sblk, rp,
                                    inv_src, inv_dst, inv_den, N);
  scatter_kernel<<<NCH, 1024, 0, stream>>>(src, dst, rp, ord, Hdst, csr,
                                           E, bins2, CE);

  // conversions (featH is independent of the hA/hB-aliased scratch)
  {
    long thr = (long)Mpad * 512 / 4;
    cvt_kernel<<<(int)((thr + 255) / 256), 256, 0, stream>>>(
        features, featH, (long)N * 512, (long)Mpad * 512);
    WArgs wa;
    int maxn = 0;
    for (int i = 0; i < 7; ++i) {
      wa.s[i] = wsrc[i]; wa.d[i] = wH[i]; wa.n[i] = wcnt[i];
      if (wcnt[i] > maxn) maxn = wcnt[i];
    }
    dim3 wg((maxn / 4 + 255) / 256, 7);
    wcvt_kernel<<<wg, 256, 0, stream>>>(wa);
  }

  const int dout[3] = {384, 256, 128};
  const _Float16* h = featH;
  int K = 512;
  const int ab = (N + 31) / 32;  // 2 node-tiles per block, one dispatch round
  for (int s = 0; s < 3; ++s) {
    const int D = dout[s];
    dim3 gg(MB, D / 128);
    // SAGE: Z = h @ sw^T ; h' = relu((sum_in Z + Z_self)*inv_den + sb)
    hgemm<_Float16><<<gg, 256, 0, stream>>>(h, wH[2 * s], hB, Mpad, K, D, nullptr, nullptr);
    if (D == 384)      agg_h<384, true><<<ab, 256, 0, stream>>>(hB, rp, csr, inv_den, sb[s], hA, N);
    else if (D == 256) agg_h<256, true><<<ab, 256, 0, stream>>>(hB, rp, csr, inv_den, sb[s], hA, N);
    else               agg_h<128, true><<<ab, 256, 0, stream>>>(hB, rp, csr, inv_den, sb[s], hA, N);
    // GraphConv: Z = (h'*inv_src) @ gw^T ; h'' = relu((sum_in Z)*inv_dst + gb)
    hgemm<_Float16><<<gg, 256, 0, stream>>>(hA, wH[2 * s + 1], hB, Mpad, D, D, inv_src, nullptr);
    if (D == 384)      agg_h<384, false><<<ab, 256, 0, stream>>>(hB, rp, csr, inv_dst, gb[s], hA, N);
    else if (D == 256) agg_h<256, false><<<ab, 256, 0, stream>>>(hB, rp, csr, inv_dst, gb[s], hA, N);
    else               agg_h<128, false><<<ab, 256, 0, stream>>>(hB, rp, csr, inv_dst, gb[s], hA, N);
    h = hA;
    K = D;
  }
  // final FC: fp32 out + bias, no relu
  dim3 gf(MB, 1);
  hgemm<float><<<gf, 256, 0, stream>>>(h, wH[6], (float*)d_out, N, 128, 128, nullptr, fc_b);
}